// Round 16
// baseline (137.897 us; speedup 1.0000x reference)
//
#include <hip/hip_runtime.h>
#include <hip/hip_bf16.h>

// out = x @ W.T + 2*b ; M=N=K=4096, fp32 in/out.
// Round 16: mega-tile waves — 4 waves x (128x128 output each) on a 256x256
// block tile. Doubles fragment reuse (each LDS read feeds 8 MFMAs, was 4):
// CU-tile LDS reads 192KB -> 128KB, moving the binding floor from LDS (3080cyc)
// to MFMA (2483cyc). acc=256 VGPR -> 1 wave/SIMD (launch_bounds(256,1)).
// Schedule = champion skeleton over 8 m-phases: read-one-ahead, A(t+2) staged
// ph0-3, B(t+2) ph4-7, vmcnt(14) drain at ph6, woven ph7 B-reloads, 2 barriers.
// Same 0-conflict swizzles (R3/R12-verified). Tripwire: VGPR>450/WRITE_SIZE
// inflation = spill -> revert to R12 champion next round.

typedef short bf16x8 __attribute__((ext_vector_type(8)));
typedef short s16x4  __attribute__((ext_vector_type(4)));
typedef short s16x8  __attribute__((ext_vector_type(8)));
typedef float f32x4  __attribute__((ext_vector_type(4)));

constexpr int MDIM = 4096, NDIM = 4096, KDIM = 4096;

typedef const __attribute__((address_space(1))) void* gas_t;
typedef __attribute__((address_space(3))) void*       las_t;

__device__ __forceinline__ short f2bf(float f) {
    __hip_bfloat16 h = __float2bfloat16(f);   // RNE
    short s; __builtin_memcpy(&s, &h, 2); return s;
}

// ---------------- pass 1: fp32 -> bf16 convert (X and W, one launch) ----------------
__global__ __launch_bounds__(256)
void cvt2_f32_bf16(const float* __restrict__ inA, const float* __restrict__ inB,
                   short* __restrict__ outA, short* __restrict__ outB, int n8each) {
    int idx    = blockIdx.x * blockDim.x + threadIdx.x;
    int stride = gridDim.x * blockDim.x;
    for (int i = idx; i < 2 * n8each; i += stride) {
        const f32x4* in4 = (i < n8each) ? (const f32x4*)inA : (const f32x4*)inB;
        s16x8*      out8 = (i < n8each) ? (s16x8*)outA      : (s16x8*)outB;
        int j = (i < n8each) ? i : i - n8each;
        f32x4 a = in4[2 * j];
        f32x4 b = in4[2 * j + 1];
        s16x8 o = { f2bf(a[0]), f2bf(a[1]), f2bf(a[2]), f2bf(a[3]),
                    f2bf(b[0]), f2bf(b[1]), f2bf(b[2]), f2bf(b[3]) };
        out8[j] = o;
    }
}

// ---------------- pass 2: 256x256 bf16 GEMM, 4 mega-tile waves ----------------
constexpr int BM = 256, BN = 256, BK = 64;
constexpr int NT  = KDIM / BK;   // 64 K-tiles
constexpr int ASZ = BM * BK;     // 16384 shorts (32 KiB) per buffer
constexpr int BSZ = BN * BK;

// read one A m-block (rows rA+M*16..+15), 2 x ds_read_b128
__device__ __forceinline__ void read_am(const short* base, int row, int c0, int c1,
                                        bf16x8 (&dst)[2]) {
    const short* p = &base[row * BK];
    dst[0] = *(const bf16x8*)(p + c0);
    dst[1] = *(const bf16x8*)(p + c1);
}

// 16 MFMA for one m-block row of the 128x128 wave tile
template <int M>
__device__ __forceinline__ void mfma_row(const bf16x8 (&af)[2], const bf16x8 (&bf)[8][2],
                                         f32x4 (&acc)[8][8]) {
    __builtin_amdgcn_s_setprio(1);
    #pragma unroll
    for (int ni = 0; ni < 8; ++ni)
        #pragma unroll
        for (int kk = 0; kk < 2; ++kk)
            acc[M][ni] = __builtin_amdgcn_mfma_f32_16x16x32_bf16(
                af[kk], bf[ni][kk], acc[M][ni], 0, 0, 0);
    __builtin_amdgcn_s_setprio(0);
}

__global__ __launch_bounds__(256, 1)
void gemm_bf16_256(const short* __restrict__ Xb, const short* __restrict__ Wb,
                   const float* __restrict__ Bv, float* __restrict__ Out)
{
    __shared__ short lds[3 * ASZ + 2 * BSZ];   // 160 KiB: A x3, B x2

    const int tid  = threadIdx.x;
    const int lane = tid & 63;
    const int wid  = tid >> 6;          // 0..3
    const int wr   = wid >> 1;          // 0..1 (M)
    const int wc   = wid & 1;           // 0..1 (N)

    // T1: XCD-chunked block swizzle (nwg=256, divisible by 8 -> bijective)
    const int bid = blockIdx.x;
    const int lin = (bid & 7) * 32 + (bid >> 3);
    const int tm0 = (lin >> 4) * BM;
    const int tn0 = (lin & 15) * BN;

    // ---- staging: linear LDS dest, inverse-swizzled global source ----
    // wave stages 8 segments (8 rows each): seg j -> rows [64*wid+8*j, +8)
    const int srow = lane >> 3;
    const int sgrn = (lane & 7) ^ srow;
    const char* xbase = (const char*)Xb;
    const char* wbase = (const char*)Wb;
    int aOff[8], bOff[8], dOff[8];
    #pragma unroll
    for (int j = 0; j < 8; ++j) {
        const int r = 64 * wid + 8 * j;
        aOff[j] = ((tm0 + r + srow) * KDIM + sgrn * 8) * 2;
        bOff[j] = ((tn0 + r + srow) * KDIM + sgrn * 8) * 2;
        dOff[j] = r * BK;
    }

    // ---- fragment read addressing (swizzled; m89-verified 16x16x32 layout) ----
    const int g   = lane >> 4;          // k-group 0..3 ; D-row group
    const int r16 = lane & 15;          // frag row ; D col
    const int c0  = ((0 + g) ^ (r16 & 7)) * 8;   // kk=0 granule (elements)
    const int c1  = ((4 + g) ^ (r16 & 7)) * 8;   // kk=1
    const int rA  = wr * 128 + r16;
    const int rB  = wc * 128 + r16;

    f32x4 acc[8][8] = {};
    bf16x8 bf[8][2];    // B-frag set [ni][kk] (reloaded in place inside ph7)
    bf16x8 a0[2];       // A m0 frags (reloaded at end of ph7)

    auto stageA = [&](int kt, int j, short* dst) {
        const size_t kb = (size_t)kt * (BK * 2);
        __builtin_amdgcn_global_load_lds((gas_t)(xbase + kb + aOff[j]),
                                         (las_t)(dst + dOff[j]), 16, 0, 0);
    };
    auto stageB = [&](int kt, int j, short* dst) {
        const size_t kb = (size_t)kt * (BK * 2);
        __builtin_amdgcn_global_load_lds((gas_t)(wbase + kb + bOff[j]),
                                         (las_t)(dst + dOff[j]), 16, 0, 0);
    };

    // buffer pointers (wave-uniform, rotated per tile)
    short* aSlot0 = (short*)&lds[0];
    short* aSlot1 = (short*)&lds[ASZ];
    short* aSlot2 = (short*)&lds[2 * ASZ];
    short* bSlot0 = (short*)&lds[3 * ASZ];
    short* bSlot1 = (short*)&lds[3 * ASZ + BSZ];

    // ---- prologue: stage B(0), A(0), B(1), A(1) (8 each) ; vmcnt(16) ----
    {
        #pragma unroll
        for (int j = 0; j < 8; ++j) stageB(0, j, bSlot0);
        #pragma unroll
        for (int j = 0; j < 8; ++j) stageA(0, j, aSlot0);
        #pragma unroll
        for (int j = 0; j < 8; ++j) stageB(1, j, bSlot1);
        #pragma unroll
        for (int j = 0; j < 8; ++j) stageA(1, j, aSlot1);
        asm volatile("s_waitcnt vmcnt(16)" ::: "memory");  // B(0),A(0) landed
        asm volatile("s_barrier" ::: "memory");
        #pragma unroll
        for (int ni = 0; ni < 8; ++ni) {
            const short* p = &bSlot0[(rB + ni * 16) * BK];
            bf[ni][0] = *(const bf16x8*)(p + c0);
            bf[ni][1] = *(const bf16x8*)(p + c1);
        }
        read_am(aSlot0, rA, c0, c1, a0);
    }

    // ---- main loop ----
    short* aCur = aSlot0; short* aNxt = aSlot1; short* aStg = aSlot2;
    short* bCur = bSlot0; short* bNxt = bSlot1;

    for (int t = 0; t < NT; ++t) {
        const bool sA = (t + 2 < NT);
        bf16x8 amE[2], amO[2];   // ping-pong A m-block frags

        // ph0: read m1 ; stage A(t+2) j0,j1 ; MFMA m0
        read_am(aCur, rA + 16, c0, c1, amO);
        if (sA) { stageA(t + 2, 0, aStg); stageA(t + 2, 1, aStg); }
        mfma_row<0>(a0, bf, acc);
        // ph1: read m2 ; stage A j2,j3 ; MFMA m1
        read_am(aCur, rA + 32, c0, c1, amE);
        if (sA) { stageA(t + 2, 2, aStg); stageA(t + 2, 3, aStg); }
        mfma_row<1>(amO, bf, acc);
        // ph2: read m3 ; stage A j4,j5 ; MFMA m2
        read_am(aCur, rA + 48, c0, c1, amO);
        if (sA) { stageA(t + 2, 4, aStg); stageA(t + 2, 5, aStg); }
        mfma_row<2>(amE, bf, acc);
        // ph3: read m4 ; stage A j6,j7 ; MFMA m3
        read_am(aCur, rA + 64, c0, c1, amE);
        if (sA) { stageA(t + 2, 6, aStg); stageA(t + 2, 7, aStg); }
        mfma_row<3>(amO, bf, acc);
        // ph4: read m5 ; stage B(t+2) j0,j1 ; MFMA m4
        read_am(aCur, rA + 80, c0, c1, amO);
        if (sA) { stageB(t + 2, 0, bCur); stageB(t + 2, 1, bCur); }
        mfma_row<4>(amE, bf, acc);
        // ph5: read m6 ; stage B j2,j3 ; MFMA m5
        read_am(aCur, rA + 96, c0, c1, amE);
        if (sA) { stageB(t + 2, 2, bCur); stageB(t + 2, 3, bCur); }
        mfma_row<5>(amO, bf, acc);
        // ph6: read m7 ; stage B j4,j5 ; vmcnt+barrier ; MFMA m6
        read_am(aCur, rA + 112, c0, c1, amO);
        if (sA) { stageB(t + 2, 4, bCur); stageB(t + 2, 5, bCur); }
        // ledger (FIFO): outstanding = A(t+1)8, B(t+1)8, A(t+2)8, B(t+2)6.
        // vmcnt(14) drains A(t+1)+B(t+1); (t+2) stays in flight.
        if (t < NT - 2) { asm volatile("s_waitcnt vmcnt(14)" ::: "memory"); }
        else            { asm volatile("s_waitcnt vmcnt(0)" ::: "memory"); }
        asm volatile("s_barrier" ::: "memory");
        mfma_row<6>(amE, bf, acc);

        // ph7: MFMA m7 with next-tile B-frag reloads WOVEN IN (1:1), then a0,
        //      then B(t+2) j6,j7 staging
        __builtin_amdgcn_s_setprio(1);
        #pragma unroll
        for (int ni = 0; ni < 8; ++ni) {
            #pragma unroll
            for (int kk = 0; kk < 2; ++kk) {
                const int cc = kk ? c1 : c0;
                acc[7][ni] = __builtin_amdgcn_mfma_f32_16x16x32_bf16(
                                 amO[kk], bf[ni][kk], acc[7][ni], 0, 0, 0);
                if (t + 1 < NT)
                    bf[ni][kk] = *(const bf16x8*)(&bNxt[(rB + ni * 16) * BK] + cc);
            }
        }
        __builtin_amdgcn_s_setprio(0);
        if (t + 1 < NT) read_am(aNxt, rA, c0, c1, a0);
        if (sA) { stageB(t + 2, 6, bCur); stageB(t + 2, 7, bCur); }
        asm volatile("s_barrier" ::: "memory");   // tile-t reads done before next stages land

        // rotate buffers
        short* tmp = aCur; aCur = aNxt; aNxt = aStg; aStg = tmp;
        tmp = bCur; bCur = bNxt; bNxt = tmp;
    }

    // ---- epilogue: + 2*bias, fp32 store ----
    float bb[8];
    #pragma unroll
    for (int ni = 0; ni < 8; ++ni)
        bb[ni] = 2.0f * Bv[tn0 + wc * 128 + ni * 16 + r16];

    #pragma unroll
    for (int mi = 0; mi < 8; ++mi) {
        #pragma unroll
        for (int r = 0; r < 4; ++r) {
            const int row = tm0 + wr * 128 + mi * 16 + g * 4 + r;
            float* orow = Out + (size_t)row * NDIM + tn0 + wc * 128 + r16;
            #pragma unroll
            for (int ni = 0; ni < 8; ++ni)
                orow[ni * 16] = acc[mi][ni][r] + bb[ni];
        }
    }
}

// ---------------- fallback: fp32 reg-staged (if ws too small) ----------------
constexpr int FBM = 128, FBN = 128, FBK = 32, LDT = FBK + 8;
__global__ __launch_bounds__(256)
void gemm_xwt_bias2(const float* __restrict__ X, const float* __restrict__ W,
                    const float* __restrict__ Bv, float* __restrict__ Out)
{
    __shared__ short As[FBM * LDT];
    __shared__ short Bs[FBN * LDT];
    const int tid  = threadIdx.x;
    const int lane = tid & 63;
    const int wid  = tid >> 6;
    const int wr   = wid >> 1;
    const int wc   = wid & 1;
    const int tm0  = blockIdx.y * FBM;
    const int tn0  = blockIdx.x * FBN;
    const int srow = tid >> 3;
    const int scol = (tid & 7) * 4;
    const int g    = lane >> 4;
    const int r16  = lane & 15;
    f32x4 acc[4][4] = {};
    const float* xg = X + (size_t)(tm0 + srow) * KDIM + scol;
    const float* wg = W + (size_t)(tn0 + srow) * KDIM + scol;
    for (int k0 = 0; k0 < KDIM; k0 += FBK) {
        #pragma unroll
        for (int i = 0; i < 4; ++i) {
            const int row = srow + 32 * i;
            f32x4 av = *(const f32x4*)(xg + (size_t)(32 * i) * KDIM + k0);
            f32x4 bv = *(const f32x4*)(wg + (size_t)(32 * i) * KDIM + k0);
            s16x4 pa = { f2bf(av[0]), f2bf(av[1]), f2bf(av[2]), f2bf(av[3]) };
            s16x4 pb = { f2bf(bv[0]), f2bf(bv[1]), f2bf(bv[2]), f2bf(bv[3]) };
            *(s16x4*)&As[row * LDT + scol] = pa;
            *(s16x4*)&Bs[row * LDT + scol] = pb;
        }
        __syncthreads();
        bf16x8 af[4], bfr[4];
        #pragma unroll
        for (int mi = 0; mi < 4; ++mi)
            af[mi] = *(const bf16x8*)&As[(wr * 64 + mi * 16 + r16) * LDT + g * 8];
        #pragma unroll
        for (int ni = 0; ni < 4; ++ni)
            bfr[ni] = *(const bf16x8*)&Bs[(wc * 64 + ni * 16 + r16) * LDT + g * 8];
        #pragma unroll
        for (int mi = 0; mi < 4; ++mi)
            #pragma unroll
            for (int ni = 0; ni < 4; ++ni)
                acc[mi][ni] = __builtin_amdgcn_mfma_f32_16x16x32_bf16(
                                  af[mi], bfr[ni], acc[mi][ni], 0, 0, 0);
        __syncthreads();
    }
    float bb[4];
    #pragma unroll
    for (int ni = 0; ni < 4; ++ni)
        bb[ni] = 2.0f * Bv[tn0 + wc * 64 + ni * 16 + r16];
    #pragma unroll
    for (int mi = 0; mi < 4; ++mi)
        #pragma unroll
        for (int r = 0; r < 4; ++r) {
            const int row = tm0 + wr * 64 + mi * 16 + g * 4 + r;
            float* orow = Out + (size_t)row * NDIM + tn0 + wc * 64 + r16;
            #pragma unroll
            for (int ni = 0; ni < 4; ++ni)
                orow[ni * 16] = acc[mi][ni][r] + bb[ni];
        }
}

extern "C" void kernel_launch(void* const* d_in, const int* in_sizes, int n_in,
                              void* d_out, int out_size, void* d_ws, size_t ws_size,
                              hipStream_t stream) {
    const float* X  = (const float*)d_in[0];
    const float* W  = (const float*)d_in[1];
    const float* Bv = (const float*)d_in[2];
    float* Out = (float*)d_out;

    const size_t nElem = (size_t)MDIM * KDIM;
    const size_t need  = 2 * nElem * sizeof(short);   // 67.1 MB

    if (ws_size >= need) {
        short* Xb = (short*)d_ws;
        short* Wb = Xb + nElem;
        const int n8 = (int)(nElem / 8);
        cvt2_f32_bf16<<<4096, 256, 0, stream>>>(X, W, Xb, Wb, n8);
        gemm_bf16_256<<<dim3(256), 256, 0, stream>>>(Xb, Wb, Bv, Out);
    } else {
        dim3 grid(NDIM / FBN, MDIM / FBM);
        gemm_xwt_bias2<<<grid, 256, 0, stream>>>(X, W, Bv, Out);
    }
}

// Round 17
// 133.379 us; speedup vs baseline: 1.0339x; 1.0339x over previous
//
#include <hip/hip_runtime.h>
#include <hip/hip_bf16.h>

// out = x @ W.T + 2*b ; M=N=K=4096, fp32 in/out.
// Round 17: R12 champion (113.4us GEMM, reproduced R15) with ONE A/B probe:
//   s_setprio(1)/(0) wrappers REMOVED. m190 measured setprio at -1.5% on
//   barrier-lockstep GEMM structures (it only pays on role-split schedules);
//   our 2-barrier/tile loop is semi-lockstep, and the 128 setprio toggles/tile
//   are pure SALU overhead + may starve the co-wave's ds_reads.
// Everything else byte-identical to R12/R15.
// Geometry axis closed by R16: reuse x TLP is register-file-capped; 2-wave
// TLP beats halved LDS traffic (121.5 vs 113.4).

typedef short bf16x8 __attribute__((ext_vector_type(8)));
typedef short s16x4  __attribute__((ext_vector_type(4)));
typedef short s16x8  __attribute__((ext_vector_type(8)));
typedef float f32x4  __attribute__((ext_vector_type(4)));

constexpr int MDIM = 4096, NDIM = 4096, KDIM = 4096;

typedef const __attribute__((address_space(1))) void* gas_t;
typedef __attribute__((address_space(3))) void*       las_t;

__device__ __forceinline__ short f2bf(float f) {
    __hip_bfloat16 h = __float2bfloat16(f);   // RNE
    short s; __builtin_memcpy(&s, &h, 2); return s;
}

// ---------------- pass 1: fp32 -> bf16 convert (X and W, one launch) ----------------
__global__ __launch_bounds__(256)
void cvt2_f32_bf16(const float* __restrict__ inA, const float* __restrict__ inB,
                   short* __restrict__ outA, short* __restrict__ outB, int n8each) {
    int idx    = blockIdx.x * blockDim.x + threadIdx.x;
    int stride = gridDim.x * blockDim.x;
    for (int i = idx; i < 2 * n8each; i += stride) {
        const f32x4* in4 = (i < n8each) ? (const f32x4*)inA : (const f32x4*)inB;
        s16x8*      out8 = (i < n8each) ? (s16x8*)outA      : (s16x8*)outB;
        int j = (i < n8each) ? i : i - n8each;
        f32x4 a = in4[2 * j];
        f32x4 b = in4[2 * j + 1];
        s16x8 o = { f2bf(a[0]), f2bf(a[1]), f2bf(a[2]), f2bf(a[3]),
                    f2bf(b[0]), f2bf(b[1]), f2bf(b[2]), f2bf(b[3]) };
        out8[j] = o;
    }
}

// ---------------- pass 2: 256x256 bf16 GEMM (16x16x32), pipelined reads ----------------
constexpr int BM = 256, BN = 256, BK = 64;
constexpr int NT  = KDIM / BK;   // 64 K-tiles
constexpr int ASZ = BM * BK;     // 16384 shorts (32 KiB) per buffer
constexpr int BSZ = BN * BK;

// read one A-quadrant (rows rA+Q*32 .. +Q*32+31) into 4 bf16x8
template <int Q>
__device__ __forceinline__ void read_aq(const short* base, int rA, int c0, int c1,
                                        bf16x8 (&dst)[2][2]) {
    #pragma unroll
    for (int m = 0; m < 2; ++m) {
        const short* p = &base[(rA + Q * 32 + m * 16) * BK];
        dst[m][0] = *(const bf16x8*)(p + c0);
        dst[m][1] = *(const bf16x8*)(p + c1);
    }
}

// 16 MFMA for one output quadrant (m, ni, kk-inner) — NO setprio (R17 A/B)
template <int Q>
__device__ __forceinline__ void mfma_quad(const bf16x8 (&af)[2][2], const bf16x8 (&bf)[4][2],
                                          f32x4 (&acc)[8][4]) {
    #pragma unroll
    for (int m = 0; m < 2; ++m)
        #pragma unroll
        for (int ni = 0; ni < 4; ++ni)
            #pragma unroll
            for (int kk = 0; kk < 2; ++kk)
                acc[Q * 2 + m][ni] = __builtin_amdgcn_mfma_f32_16x16x32_bf16(
                    af[m][kk], bf[ni][kk], acc[Q * 2 + m][ni], 0, 0, 0);
}

__global__ __launch_bounds__(512, 2)
void gemm_bf16_256(const short* __restrict__ Xb, const short* __restrict__ Wb,
                   const float* __restrict__ Bv, float* __restrict__ Out)
{
    __shared__ short lds[3 * ASZ + 2 * BSZ];   // 160 KiB: A x3, B x2

    const int tid  = threadIdx.x;
    const int lane = tid & 63;
    const int wid  = tid >> 6;          // 0..7
    const int wr   = wid >> 2;          // 0..1 (M)
    const int wc   = wid & 3;           // 0..3 (N)

    // T1: XCD-chunked block swizzle (nwg=256, divisible by 8 -> bijective)
    const int bid = blockIdx.x;
    const int lin = (bid & 7) * 32 + (bid >> 3);
    const int tm0 = (lin >> 4) * BM;
    const int tn0 = (lin & 15) * BN;

    // ---- staging: linear LDS dest, inverse-swizzled global source ----
    const int srow = lane >> 3;
    const int sgrn = (lane & 7) ^ srow;
    const char* xbase = (const char*)Xb;
    const char* wbase = (const char*)Wb;
    int aOff[2][2], bOff[2][2], dOff[2][2];
    #pragma unroll
    for (int h = 0; h < 2; ++h) {
        #pragma unroll
        for (int j = 0; j < 2; ++j) {
            const int r = h * 128 + (2 * wid + j) * 8;   // segment base row (mult of 8)
            aOff[h][j] = ((tm0 + r + srow) * KDIM + sgrn * 8) * 2;
            bOff[h][j] = ((tn0 + r + srow) * KDIM + sgrn * 8) * 2;
            dOff[h][j] = r * BK;
        }
    }

    // ---- fragment read addressing (swizzled; m89-verified 16x16x32 layout) ----
    const int g   = lane >> 4;          // k-group 0..3 ; D-row group
    const int r16 = lane & 15;          // frag row ; D col
    const int c0  = ((0 + g) ^ (r16 & 7)) * 8;   // kk=0 granule (elements)
    const int c1  = ((4 + g) ^ (r16 & 7)) * 8;   // kk=1
    const int rA  = wr * 128 + r16;
    const int rB  = wc * 64  + r16;

    f32x4 acc[8][4] = {};
    bf16x8 bf[4][2];    // SINGLE B-frag set (reloaded in place inside ph3)
    bf16x8 a0[2][2];    // SINGLE A-q0 set  (reloaded in place at end of ph3)

    auto stageA = [&](int kt, int h, short* dst) {
        const size_t kb = (size_t)kt * (BK * 2);
        __builtin_amdgcn_global_load_lds((gas_t)(xbase + kb + aOff[h][0]),
                                         (las_t)(dst + dOff[h][0]), 16, 0, 0);
        __builtin_amdgcn_global_load_lds((gas_t)(xbase + kb + aOff[h][1]),
                                         (las_t)(dst + dOff[h][1]), 16, 0, 0);
    };
    auto stageB = [&](int kt, int h, short* dst) {
        const size_t kb = (size_t)kt * (BK * 2);
        __builtin_amdgcn_global_load_lds((gas_t)(wbase + kb + bOff[h][0]),
                                         (las_t)(dst + dOff[h][0]), 16, 0, 0);
        __builtin_amdgcn_global_load_lds((gas_t)(wbase + kb + bOff[h][1]),
                                         (las_t)(dst + dOff[h][1]), 16, 0, 0);
    };

    // buffer pointers (wave-uniform, rotated per tile)
    short* aSlot0 = (short*)&lds[0];
    short* aSlot1 = (short*)&lds[ASZ];
    short* aSlot2 = (short*)&lds[2 * ASZ];
    short* bSlot0 = (short*)&lds[3 * ASZ];
    short* bSlot1 = (short*)&lds[3 * ASZ + BSZ];

    // ---- prologue: stage B(0), A(0), B(1), A(1) ; vmcnt(8) -> (0) landed ----
    {
        #pragma unroll
        for (int h = 0; h < 2; ++h) stageB(0, h, bSlot0);
        #pragma unroll
        for (int h = 0; h < 2; ++h) stageA(0, h, aSlot0);
        #pragma unroll
        for (int h = 0; h < 2; ++h) stageB(1, h, bSlot1);
        #pragma unroll
        for (int h = 0; h < 2; ++h) stageA(1, h, aSlot1);
        asm volatile("s_waitcnt vmcnt(8)" ::: "memory");   // B(0),A(0) landed; B(1),A(1) in flight
        asm volatile("s_barrier" ::: "memory");
        #pragma unroll
        for (int ni = 0; ni < 4; ++ni) {
            const short* p = &bSlot0[(rB + ni * 16) * BK];
            bf[ni][0] = *(const bf16x8*)(p + c0);
            bf[ni][1] = *(const bf16x8*)(p + c1);
        }
        read_aq<0>(aSlot0, rA, c0, c1, a0);
    }

    // ---- main loop: per tile t, buffers: A reads aCur, next-tile reads aNxt,
    //      A(t+2) staged into aStg; B reads (woven) bNxt, B(t+2) staged into bCur.
    short* aCur = aSlot0; short* aNxt = aSlot1; short* aStg = aSlot2;
    short* bCur = bSlot0; short* bNxt = bSlot1;

    for (int t = 0; t < NT; ++t) {
        // ---- ph0: read A(t,q1) ; stage A(t+2) both halves ; MFMA q0 (regs)
        bf16x8 aq1[2][2];
        read_aq<1>(aCur, rA, c0, c1, aq1);
        if (t + 2 < NT) { stageA(t + 2, 0, aStg); stageA(t + 2, 1, aStg); }
        mfma_quad<0>(a0, bf, acc);

        // ---- ph1: read A(t,q2) ; stage B(t+2) h0 ; MFMA q1
        bf16x8 aq2[2][2];
        read_aq<2>(aCur, rA, c0, c1, aq2);
        if (t + 2 < NT) stageB(t + 2, 0, bCur);
        mfma_quad<1>(aq1, bf, acc);

        // ---- ph2: read A(t,q3) ; stage B(t+2) h1 ; vmcnt+barrier ; MFMA q2
        bf16x8 aq3[2][2];
        read_aq<3>(aCur, rA, c0, c1, aq3);
        if (t + 2 < NT) stageB(t + 2, 1, bCur);
        // ledger (FIFO): outstanding here = A(t+1)4, B(t+1)4, A(t+2)4, B(t+2)4.
        // vmcnt(8) drains oldest 8 = A(t+1)+B(t+1); (t+2) stays in flight.
        // A-slack 6 phases (staged t-1.ph0, drained t.ph2-end).
        if (t < NT - 2) { asm volatile("s_waitcnt vmcnt(8)" ::: "memory"); }
        else            { asm volatile("s_waitcnt vmcnt(0)" ::: "memory"); }
        asm volatile("s_barrier" ::: "memory");
        mfma_quad<2>(aq2, bf, acc);

        // ---- ph3: MFMA q3 with next-tile B-frag reloads WOVEN IN
        #pragma unroll
        for (int ni = 0; ni < 4; ++ni) {
            #pragma unroll
            for (int kk = 0; kk < 2; ++kk) {
                const int cc = kk ? c1 : c0;
                acc[6][ni] = __builtin_amdgcn_mfma_f32_16x16x32_bf16(
                                 aq3[0][kk], bf[ni][kk], acc[6][ni], 0, 0, 0);
                acc[7][ni] = __builtin_amdgcn_mfma_f32_16x16x32_bf16(
                                 aq3[1][kk], bf[ni][kk], acc[7][ni], 0, 0, 0);
                if (t + 1 < NT)
                    bf[ni][kk] = *(const bf16x8*)(&bNxt[(rB + ni * 16) * BK] + cc);
            }
        }
        if (t + 1 < NT) read_aq<0>(aNxt, rA, c0, c1, a0);
        asm volatile("s_barrier" ::: "memory");   // tile-t reads done before next stages land

        // rotate buffers
        short* tmp = aCur; aCur = aNxt; aNxt = aStg; aStg = tmp;
        tmp = bCur; bCur = bNxt; bNxt = tmp;
    }

    // ---- epilogue: + 2*bias, fp32 store ----
    float bb[4];
    #pragma unroll
    for (int ni = 0; ni < 4; ++ni)
        bb[ni] = 2.0f * Bv[tn0 + wc * 64 + ni * 16 + r16];

    #pragma unroll
    for (int mi = 0; mi < 8; ++mi) {
        #pragma unroll
        for (int r = 0; r < 4; ++r) {
            const int row = tm0 + wr * 128 + mi * 16 + g * 4 + r;
            float* orow = Out + (size_t)row * NDIM + tn0 + wc * 64 + r16;
            #pragma unroll
            for (int ni = 0; ni < 4; ++ni)
                orow[ni * 16] = acc[mi][ni][r] + bb[ni];
        }
    }
}

// ---------------- fallback: fp32 reg-staged (if ws too small) ----------------
constexpr int FBM = 128, FBN = 128, FBK = 32, LDT = FBK + 8;
__global__ __launch_bounds__(256)
void gemm_xwt_bias2(const float* __restrict__ X, const float* __restrict__ W,
                    const float* __restrict__ Bv, float* __restrict__ Out)
{
    __shared__ short As[FBM * LDT];
    __shared__ short Bs[FBN * LDT];
    const int tid  = threadIdx.x;
    const int lane = tid & 63;
    const int wid  = tid >> 6;
    const int wr   = wid >> 1;
    const int wc   = wid & 1;
    const int tm0  = blockIdx.y * FBM;
    const int tn0  = blockIdx.x * FBN;
    const int srow = tid >> 3;
    const int scol = (tid & 7) * 4;
    const int g    = lane >> 4;
    const int r16  = lane & 15;
    f32x4 acc[4][4] = {};
    const float* xg = X + (size_t)(tm0 + srow) * KDIM + scol;
    const float* wg = W + (size_t)(tn0 + srow) * KDIM + scol;
    for (int k0 = 0; k0 < KDIM; k0 += FBK) {
        #pragma unroll
        for (int i = 0; i < 4; ++i) {
            const int row = srow + 32 * i;
            f32x4 av = *(const f32x4*)(xg + (size_t)(32 * i) * KDIM + k0);
            f32x4 bv = *(const f32x4*)(wg + (size_t)(32 * i) * KDIM + k0);
            s16x4 pa = { f2bf(av[0]), f2bf(av[1]), f2bf(av[2]), f2bf(av[3]) };
            s16x4 pb = { f2bf(bv[0]), f2bf(bv[1]), f2bf(bv[2]), f2bf(bv[3]) };
            *(s16x4*)&As[row * LDT + scol] = pa;
            *(s16x4*)&Bs[row * LDT + scol] = pb;
        }
        __syncthreads();
        bf16x8 af[4], bfr[4];
        #pragma unroll
        for (int mi = 0; mi < 4; ++mi)
            af[mi] = *(const bf16x8*)&As[(wr * 64 + mi * 16 + r16) * LDT + g * 8];
        #pragma unroll
        for (int ni = 0; ni < 4; ++ni)
            bfr[ni] = *(const bf16x8*)&Bs[(wc * 64 + ni * 16 + r16) * LDT + g * 8];
        #pragma unroll
        for (int mi = 0; mi < 4; ++mi)
            #pragma unroll
            for (int ni = 0; ni < 4; ++ni)
                acc[mi][ni] = __builtin_amdgcn_mfma_f32_16x16x32_bf16(
                                  af[mi], bfr[ni], acc[mi][ni], 0, 0, 0);
        __syncthreads();
    }
    float bb[4];
    #pragma unroll
    for (int ni = 0; ni < 4; ++ni)
        bb[ni] = 2.0f * Bv[tn0 + wc * 64 + ni * 16 + r16];
    #pragma unroll
    for (int mi = 0; mi < 4; ++mi)
        #pragma unroll
        for (int r = 0; r < 4; ++r) {
            const int row = tm0 + wr * 64 + mi * 16 + g * 4 + r;
            float* orow = Out + (size_t)row * NDIM + tn0 + wc * 64 + r16;
            #pragma unroll
            for (int ni = 0; ni < 4; ++ni)
                orow[ni * 16] = acc[mi][ni][r] + bb[ni];
        }
}

extern "C" void kernel_launch(void* const* d_in, const int* in_sizes, int n_in,
                              void* d_out, int out_size, void* d_ws, size_t ws_size,
                              hipStream_t stream) {
    const float* X  = (const float*)d_in[0];
    const float* W  = (const float*)d_in[1];
    const float* Bv = (const float*)d_in[2];
    float* Out = (float*)d_out;

    const size_t nElem = (size_t)MDIM * KDIM;
    const size_t need  = 2 * nElem * sizeof(short);   // 67.1 MB

    if (ws_size >= need) {
        short* Xb = (short*)d_ws;
        short* Wb = Xb + nElem;
        const int n8 = (int)(nElem / 8);
        cvt2_f32_bf16<<<4096, 256, 0, stream>>>(X, W, Xb, Wb, n8);
        gemm_bf16_256<<<dim3(256), 512, 0, stream>>>(Xb, Wb, Bv, Out);
    } else {
        dim3 grid(NDIM / FBN, MDIM / FBM);
        gemm_xwt_bias2<<<grid, 256, 0, stream>>>(X, W, Bv, Out);
    }
}